// Round 1
// baseline (255.694 us; speedup 1.0000x reference)
//
#include <hip/hip_runtime.h>
#include <math.h>

#define NB   64
#define NL   512
#define ND   768
#define NP   128
#define NHID 1024
#define NTOK (NB * NL)

__device__ __forceinline__ float4 f4add(float4 a, float4 b) {
    return make_float4(a.x + b.x, a.y + b.y, a.z + b.z, a.w + b.w);
}

__device__ __forceinline__ float nanfix(float x) { return (x == x) ? x : 0.0f; }

__device__ __forceinline__ float wave_sum(float x) {
    #pragma unroll
    for (int off = 32; off > 0; off >>= 1) x += __shfl_xor(x, off, 64);
    return x;
}

// One 64-lane wave per token. Lane layout:
//   token path: 12 floats/lane at h = lane*12   (768 total)
//   pos   path:  4 floats/lane at h = 768 + lane*4 (256 total)
__global__ __launch_bounds__(256)
void molt_embed_ln(
    const int*   __restrict__ input_ids,
    const int*   __restrict__ token_type_ids,
    const int*   __restrict__ pos_embed_ids,
    const float* __restrict__ lp_embeds,
    const int*   __restrict__ p_ring,
    const int*   __restrict__ p_charge,
    const int*   __restrict__ p_hyb,
    const int*   __restrict__ p_chir,
    const int*   __restrict__ p_arom,
    const int*   __restrict__ p_conj,
    const int*   __restrict__ p_stereo,
    const float* __restrict__ mol_features,
    const float* __restrict__ target_values,
    const float* __restrict__ emb_table,
    const float* __restrict__ type_table,
    const float* __restrict__ ring_tab,
    const float* __restrict__ charge_tab,
    const float* __restrict__ hyb_tab,
    const float* __restrict__ chir_tab,
    const float* __restrict__ arom_tab,
    const float* __restrict__ conj_tab,
    const float* __restrict__ stereo_tab,
    const float* __restrict__ ln_gamma,
    const float* __restrict__ ln_beta,
    float*       __restrict__ out)
{
    const int lane = threadIdx.x & 63;
    int t = (blockIdx.x << 2) + (threadIdx.x >> 6);
    t = __builtin_amdgcn_readfirstlane(t);   // wave-uniform -> scalarize index loads
    const int b = t >> 9;                    // t / L, L=512

    // per-token scalars
    const int id   = input_ids[t];
    const int tt   = token_type_ids[t];
    const int ir   = p_ring[t];
    const int ic   = p_charge[t];
    const int ihy  = p_hyb[t];
    const int ichr = p_chir[t];
    const int ia   = p_arom[t];
    const int icj  = p_conj[t];
    const int ist  = p_stereo[t];

    float scale = 1.0f;
    if (tt == 5)      scale = 1.0f + mol_features[t];   // FEAT
    else if (tt == 6) scale = 1.0f + target_values[t];  // TGT

    // ---- token path: 3x float4 per lane ----
    const int h0 = lane * 12;   // 48B offset, 16B aligned
    const float4* e  = (const float4*)(emb_table  + (size_t)id   * ND + h0);
    const float4* ty = (const float4*)(type_table + (size_t)tt   * ND + h0);
    const float4* r  = (const float4*)(ring_tab   + (size_t)ir   * ND + h0);
    const float4* c  = (const float4*)(charge_tab + (size_t)ic   * ND + h0);
    const float4* hy = (const float4*)(hyb_tab    + (size_t)ihy  * ND + h0);
    const float4* ch = (const float4*)(chir_tab   + (size_t)ichr * ND + h0);
    const float4* ar = (const float4*)(arom_tab   + (size_t)ia   * ND + h0);
    const float4* cj = (const float4*)(conj_tab   + (size_t)icj  * ND + h0);
    const float4* st = (const float4*)(stereo_tab + (size_t)ist  * ND + h0);

    float4 v[4];
    #pragma unroll
    for (int j = 0; j < 3; ++j) {
        float4 a = e[j];
        float4 s = f4add(f4add(f4add(ty[j], r[j]), f4add(c[j], hy[j])),
                         f4add(f4add(ch[j], ar[j]), f4add(cj[j], st[j])));
        float4 q;
        q.x = fmaf(a.x, scale, s.x);
        q.y = fmaf(a.y, scale, s.y);
        q.z = fmaf(a.z, scale, s.z);
        q.w = fmaf(a.w, scale, s.w);
        v[j] = q;
    }

    // ---- pos path: 1x float4 per lane ----
    {
        const int local = lane << 2;        // 0..255
        const int kk    = local >> 7;       // 0 or 1
        const int pp    = local & 127;
        const int pid   = pos_embed_ids[(t << 1) + kk];
        float4 a = *(const float4*)(lp_embeds + ((size_t)(b * NL + pid)) * NP + pp);
        a.x = nanfix(a.x); a.y = nanfix(a.y); a.z = nanfix(a.z); a.w = nanfix(a.w);
        v[3] = a;
    }

    // ---- layernorm over 1024, all-register two-pass ----
    float s = 0.0f;
    #pragma unroll
    for (int j = 0; j < 4; ++j) s += v[j].x + v[j].y + v[j].z + v[j].w;
    s = wave_sum(s);
    const float mean = s * (1.0f / (float)NHID);

    float q2 = 0.0f;
    #pragma unroll
    for (int j = 0; j < 4; ++j) {
        float dx = v[j].x - mean, dy = v[j].y - mean,
              dz = v[j].z - mean, dw = v[j].w - mean;
        q2 += dx * dx + dy * dy + dz * dz + dw * dw;
    }
    q2 = wave_sum(q2);
    const float var = q2 * (1.0f / (float)NHID);
    const float inv = 1.0f / sqrtf(var + 1e-12f);

    // ---- write ----
    float* orow = out + (size_t)t * NHID;
    const float4* g0 = (const float4*)(ln_gamma + h0);
    const float4* b0 = (const float4*)(ln_beta  + h0);
    float4* o0 = (float4*)(orow + h0);
    #pragma unroll
    for (int j = 0; j < 3; ++j) {
        float4 g = g0[j], be = b0[j], q;
        q.x = fmaf((v[j].x - mean) * inv, g.x, be.x);
        q.y = fmaf((v[j].y - mean) * inv, g.y, be.y);
        q.z = fmaf((v[j].z - mean) * inv, g.z, be.z);
        q.w = fmaf((v[j].w - mean) * inv, g.w, be.w);
        o0[j] = q;
    }
    {
        const int hp = ND + (lane << 2);
        float4 g = *(const float4*)(ln_gamma + hp);
        float4 be = *(const float4*)(ln_beta + hp);
        float4 q;
        q.x = fmaf((v[3].x - mean) * inv, g.x, be.x);
        q.y = fmaf((v[3].y - mean) * inv, g.y, be.y);
        q.z = fmaf((v[3].z - mean) * inv, g.z, be.z);
        q.w = fmaf((v[3].w - mean) * inv, g.w, be.w);
        *(float4*)(orow + hp) = q;
    }
}

extern "C" void kernel_launch(void* const* d_in, const int* in_sizes, int n_in,
                              void* d_out, int out_size, void* d_ws, size_t ws_size,
                              hipStream_t stream) {
    (void)in_sizes; (void)n_in; (void)out_size; (void)d_ws; (void)ws_size;
    molt_embed_ln<<<NTOK / 4, 256, 0, stream>>>(
        (const int*)d_in[0],  (const int*)d_in[1],  (const int*)d_in[2],
        (const float*)d_in[3],
        (const int*)d_in[4],  (const int*)d_in[5],  (const int*)d_in[6],
        (const int*)d_in[7],  (const int*)d_in[8],  (const int*)d_in[9],
        (const int*)d_in[10],
        (const float*)d_in[11], (const float*)d_in[12],
        (const float*)d_in[13], (const float*)d_in[14], (const float*)d_in[15],
        (const float*)d_in[16], (const float*)d_in[17], (const float*)d_in[18],
        (const float*)d_in[19], (const float*)d_in[20], (const float*)d_in[21],
        (const float*)d_in[22], (const float*)d_in[23],
        (float*)d_out);
}